// Round 8
// baseline (374.785 us; speedup 1.0000x reference)
//
#include <hip/hip_runtime.h>
#include <cmath>
#include <algorithm>

#define NUM_LEVELS 16
#define TABLE_SIZE 524288
#define TMASK (TABLE_SIZE - 1)
#define HASH_PRIME 2654435761u
#define T_SAMPLES 192
#define BLOCK 256
#define PTS 64          // points per tile; 4 waves split the 16 levels
#define CHUNK 4096      // entries per conversion chunk
#define N_RAYS 8192

typedef _Float16 f16;
typedef f16 f16x4 __attribute__((ext_vector_type(4)));
typedef f16 f16x8 __attribute__((ext_vector_type(8)));
typedef float f32x4 __attribute__((ext_vector_type(4)));

// mode per level: 0 = plain f16 entries (8B), 1 = quad-replicated 32B slots,
//                 2 = hashed, plain f16 entries (8B)
struct LvlParams {
    float s[NUM_LEVELS];
    int   res[NUM_LEVELS];
    int   mode[NUM_LEVELS];
    int   offB[NUM_LEVELS];   // BYTE offset of level table in embq (4096-aligned)
    int   used[NUM_LEVELS];   // entries actually referenced at this level
};

#define C_10L2E  14.42695040888963f          // 10*log2(e)
#define C_LN2_01 0.0693147180559945f         // ln(2)*0.1

// base-2 HW transcendentals (v_exp_f32 / v_log_f32 are base-2 on AMD)
#define EXP2F(x) __builtin_amdgcn_exp2f(x)
#define LOG2F(x) __builtin_amdgcn_logf(x)

// Raw barrier: LDS visibility only (lgkmcnt). Deliberately NOT __syncthreads():
// that drains vmcnt(0) and would kill the cross-barrier gather pipeline.
// Global loads target VGPRs (no cross-thread visibility), so vmcnt may stay hot.
#define BARRIER() do { asm volatile("s_waitcnt lgkmcnt(0)" ::: "memory"); \
                       __builtin_amdgcn_s_barrier(); } while (0)

// Wave->level assignment, balanced by gather cost. li=2,3 are the EXPENSIVE
// levels (hashed/quad): they are pre-issued before the previous tile's MFMA so
// their latency hides under compute; li=0,1 are L1-resident cheapies issued late.
__device__ __constant__ const int LVL[4][4] = {
    {0, 1, 8, 13},
    {2, 3, 7, 14},
    {4, 5, 6, 15},
    {9, 10, 11, 12},
};

// Packed-f16 bilinear lerp: corners arrive as packed f16 pairs straight from
// the gather (no unpack/dequant).
__device__ __forceinline__ f16x4 lerp4h(f16x4 c00, f16x4 c01, f16x4 c10, f16x4 c11,
                                        float fx, float fy) {
    float gx = 1.0f - fx, gy = 1.0f - fy;
    f16 w00 = (f16)(gx * gy), w01 = (f16)(gx * fy);
    f16 w10 = (f16)(fx * gy), w11 = (f16)(fx * fy);
    f16x4 v00 = {w00, w00, w00, w00}, v01 = {w01, w01, w01, w01};
    f16x4 v10 = {w10, w10, w10, w10}, v11 = {w11, w11, w11, w11};
    return c00 * v00 + c01 * v01 + c10 * v10 + c11 * v11;
}

// fp32 fallback lerp (QT=false path), result rounded to f16 for the MFMA.
__device__ __forceinline__ f16x4 lerp4f(f32x4 c00, f32x4 c01, f32x4 c10, f32x4 c11,
                                        float fx, float fy) {
    float w00 = (1.0f - fx) * (1.0f - fy), w01 = (1.0f - fx) * fy;
    float w10 = fx * (1.0f - fy),          w11 = fx * fy;
    f32x4 a = c00 * w00 + c01 * w01 + c10 * w10 + c11 * w11;
    return __builtin_convertvector(a, f16x4);
}

// ---- prep_tables (merged with W0 pack + per-ray setup) ----
__global__ void prep_tables(const float* __restrict__ emb, char* __restrict__ embq,
                            const float* __restrict__ W0, f16* __restrict__ w0f,
                            const float* __restrict__ x, float* __restrict__ rayBuf,
                            const LvlParams lp) {
    const int t = threadIdx.x;
    if (blockIdx.x == 0 && blockIdx.y == 0) {
        // pack W0 into MFMA-B-fragment f16 order
        #pragma unroll
        for (int i = 0; i < 16; ++i) {
            int f = t * 16 + i;
            int j = f & 7, lx = (f >> 3) & 15, q = (f >> 7) & 3, nt = (f >> 9) & 3, kc = f >> 11;
            w0f[f] = (f16)W0[(kc * 32 + q * 8 + j) * 64 + (nt * 16 + lx)];
        }
    }
    if (blockIdx.y == 1 && blockIdx.x < (N_RAYS / 256)) {
        const int ray = blockIdx.x * 256 + t;
        const float2 o  = *(const float2*)(x + (size_t)ray * (T_SAMPLES * 2));
        const float2 ep = *(const float2*)(x + (size_t)ray * (T_SAMPLES * 2) + (T_SAMPLES - 1) * 2);
        float rdx = ep.x - o.x, rdy = ep.y - o.y;
        float inv = 1.0f / sqrtf(rdx * rdx + rdy * rdy);
        f32x4 rb; rb.x = o.x; rb.y = o.y; rb.z = rdx * inv; rb.w = rdy * inv;
        *(f32x4*)(rayBuf + (size_t)ray * 4) = rb;
    }
    const int l    = blockIdx.y;
    const int used = lp.used[l];
    const int base = blockIdx.x * CHUNK;          // entry base within level
    if (base >= used) return;
    const float* src = emb + (size_t)l * TABLE_SIZE * 4;
    char* dst = embq + lp.offB[l];
    if (lp.mode[l] == 1) {
        const int res = lp.res[l];
        #pragma unroll
        for (int i = 0; i < 16; ++i) {
            int e = base + t + 256 * i;
            if (e < used) {
                f32x4 v00 = *(const f32x4*)(src + (size_t)e * 4);
                f32x4 v10 = *(const f32x4*)(src + (size_t)(e + 1) * 4);
                f32x4 v01 = *(const f32x4*)(src + (size_t)(e + res) * 4);
                f32x4 v11 = *(const f32x4*)(src + (size_t)(e + res + 1) * 4);
                f16x4 a = __builtin_convertvector(v00, f16x4);
                f16x4 b = __builtin_convertvector(v10, f16x4);
                f16x4 c = __builtin_convertvector(v01, f16x4);
                f16x4 d = __builtin_convertvector(v11, f16x4);
                f16x8 q0 = __builtin_shufflevector(a, b, 0, 1, 2, 3, 4, 5, 6, 7);
                f16x8 q1 = __builtin_shufflevector(c, d, 0, 1, 2, 3, 4, 5, 6, 7);
                *(f16x8*)(dst + ((size_t)e << 5))      = q0;
                *(f16x8*)(dst + ((size_t)e << 5) + 16) = q1;
            }
        }
    } else {
        #pragma unroll
        for (int i = 0; i < 16; ++i) {
            int e = base + t + 256 * i;
            if (e < used) {
                f32x4 v = *(const f32x4*)(src + (size_t)e * 4);
                *(f16x4*)(dst + (size_t)e * 8) = __builtin_convertvector(v, f16x4);
            }
        }
    }
}

// One ray (192 points = 3 tiles of 64) per block; 3-tile software pipeline:
// the expensive gathers (li=2,3) of tile i+1 are issued before tile i's MFMA
// and their latency hides under the MFMA+softplus epilogue.
template<bool QT>
__launch_bounds__(BLOCK, 8)
__global__ void nerf_fused(const float* __restrict__ x,
                           const float* __restrict__ emb,
                           const char* __restrict__ embq,
                           const f16* __restrict__ w0f,
                           const float* __restrict__ rayBuf,
                           const float* __restrict__ b0,
                           const float* __restrict__ W1,
                           const float* __restrict__ b1,
                           float* __restrict__ out,
                           const LvlParams lp) {
    // Paired feats tile: feT2[pair][point][8] -> MFMA A-fragment = 1 ds_read_b128.
    __shared__ __align__(16) f16 feT2[8 * PTS * 8];   // 8 KB
    __shared__ __align__(16) f16 w0lds[4096];         // 8 KB

    const int tid  = threadIdx.x;
    const int lane = tid & 63;
    const int w    = __builtin_amdgcn_readfirstlane(tid >> 6);   // wave-uniform

    // ---- W0 staging loads FIRST (oldest in vmcnt FIFO) ----
    f16x8 wreg0, wreg1;
    {
        const f16x8* wp = (const f16x8*)(w0f + (size_t)tid * 16);
        wreg0 = wp[0]; wreg1 = wp[1];
    }

    const int ray = blockIdx.x;                       // ONE ray per block

    f32x4 rb;                                         // {ox, oy, rdx_n, rdy_n}
    if (QT) {
        rb = *(const f32x4*)(rayBuf + (size_t)ray * 4);
    } else {
        const float2 o  = *(const float2*)(x + (size_t)ray * (T_SAMPLES * 2));
        const float2 ep = *(const float2*)(x + (size_t)ray * (T_SAMPLES * 2) + (T_SAMPLES - 1) * 2);
        float rdx = ep.x - o.x, rdy = ep.y - o.y;
        float inv = 1.0f / sqrtf(rdx * rdx + rdy * rdy);
        rb.x = o.x; rb.y = o.y; rb.z = rdx * inv; rb.w = rdy * inv;
    }

    // ---- epilogue constants (issued early, consumed after first barrier) ----
    const int lx = lane & 15, q = lane >> 4;
    float b0l2[4], w1l2[4];
    #pragma unroll
    for (int nt = 0; nt < 4; ++nt) {
        b0l2[nt] = b0[nt * 16 + lx] * C_10L2E;
        w1l2[nt] = W1[nt * 16 + lx] * C_LN2_01;
    }
    const float b1v = b1[0];
    const int p = w * 16 + lx;

    // ---- MLP + epilogue for one staged tile ----
    auto mfma_epi = [&](int tileIdx) {
        f32x4 acc[4];
        #pragma unroll
        for (int nt = 0; nt < 4; ++nt) acc[nt] = (f32x4)(0.0f);
        #pragma unroll
        for (int kc = 0; kc < 2; ++kc) {
            f16x8 afr = *(const f16x8*)&feT2[((kc * 4 + q) * PTS + p) * 8];
            #pragma unroll
            for (int nt = 0; nt < 4; ++nt) {
                f16x8 bfr = *(const f16x8*)&w0lds[(size_t)(((kc * 4 + nt) * 4 + q) * 16 + lx) * 8];
                acc[nt] = __builtin_amdgcn_mfma_f32_16x16x32_f16(afr, bfr, acc[nt], 0, 0, 0);
            }
        }
        const float d0 = (float)(1.0 / 192.0);
        const float d1 = (float)(2.0 / 191.0);
        float part[4];
        #pragma unroll
        for (int r = 0; r < 4; ++r) {
            float pp = 0.0f;
            #pragma unroll
            for (int nt = 0; nt < 4; ++nt) {
                float t2 = fmaf(acc[nt][r], C_10L2E, b0l2[nt]);
                float e2 = EXP2F(-fabsf(t2));
                float sp = fmaxf(t2, 0.0f) + LOG2F(1.0f + e2);
                pp = fmaf(sp, w1l2[nt], pp);
            }
            pp += __shfl_xor(pp, 1, 64);
            pp += __shfl_xor(pp, 2, 64);
            pp += __shfl_xor(pp, 4, 64);
            pp += __shfl_xor(pp, 8, 64);
            part[r] = pp;
        }
        if (lx == 0) {
            const int tt0 = tileIdx * PTS + w * 16 + q * 4;   // t within ray
            const int g0  = ray * T_SAMPLES + tt0;
            const float dd0 = d0 * C_LN2_01, dd1 = d1 * C_LN2_01;
            f32x4 ov;
            #pragma unroll
            for (int r = 0; r < 4; ++r) {
                float t2 = (part[r] + b1v) * C_10L2E;
                float e2 = EXP2F(-fabsf(t2));
                float sp = fmaxf(t2, 0.0f) + LOG2F(1.0f + e2);
                ov[r] = sp * ((r == 0 && tt0 == 0) ? dd0 : dd1);
            }
            *(f32x4*)(out + g0) = ov;
        }
    };

    float ux, uy;
    f16x4 c00[4], c01[4], c10[4], c11[4];
    float fxs[4], fys[4];

#define U_SETUP(IT)                                                         \
    {   const float z = (float)((double)((IT) * PTS + lane) * (2.0 / 191.0)); \
        float px = fminf(fmaxf(rb.x + rb.z * z, -1.0f), 1.0f);              \
        float py = fminf(fmaxf(rb.y + rb.w * z, -1.0f), 1.0f);              \
        ux = (px + 1.0f) * 0.5f; uy = (py + 1.0f) * 0.5f; }

#define ISSUE_LEVEL(LI)                                                     \
    {   const int l = LVL[w][LI];                                           \
        const int mode = lp.mode[l];                                        \
        const float s = lp.s[l];                                            \
        float posx = ux * s + 0.5f, posy = uy * s + 0.5f;                   \
        float pfx = floorf(posx), pfy = floorf(posy);                       \
        fxs[LI] = posx - pfx; fys[LI] = posy - pfy;                         \
        int cx = (int)pfx, cy = (int)pfy;                                   \
        const char* lb = embq + lp.offB[l];                                 \
        if (mode == 2) {                                                    \
            unsigned hy0 = (unsigned)cy * HASH_PRIME;                       \
            unsigned hy1 = hy0 + HASH_PRIME;                                \
            int iA  = (int)(((unsigned)cx ^ hy0) & TMASK);                  \
            int iB  = (int)(((unsigned)cx ^ hy1) & TMASK);                  \
            int iA1 = (int)(((unsigned)(cx + 1) ^ hy0) & TMASK);            \
            int iB1 = (int)(((unsigned)(cx + 1) ^ hy1) & TMASK);            \
            c00[LI] = *(const f16x4*)(lb + ((size_t)iA  << 3));             \
            c01[LI] = *(const f16x4*)(lb + ((size_t)iB  << 3));             \
            c10[LI] = *(const f16x4*)(lb + ((size_t)iA1 << 3));             \
            c11[LI] = *(const f16x4*)(lb + ((size_t)iB1 << 3));             \
        } else if (mode == 1) {                                             \
            int i00 = cy * lp.res[l] + cx;                                  \
            f16x8 q0 = *(const f16x8*)(lb + ((size_t)i00 << 5));            \
            f16x8 q1 = *(const f16x8*)(lb + ((size_t)i00 << 5) + 16);       \
            c00[LI] = __builtin_shufflevector(q0, q0, 0, 1, 2, 3);          \
            c10[LI] = __builtin_shufflevector(q0, q0, 4, 5, 6, 7);          \
            c01[LI] = __builtin_shufflevector(q1, q1, 0, 1, 2, 3);          \
            c11[LI] = __builtin_shufflevector(q1, q1, 4, 5, 6, 7);          \
        } else {                                                            \
            const int res = lp.res[l];                                      \
            int i00 = cy * res + cx;                                        \
            const f16x4* tb = (const f16x4*)lb;                             \
            c00[LI] = tb[i00];       c10[LI] = tb[i00 + 1];                 \
            c01[LI] = tb[i00 + res]; c11[LI] = tb[i00 + res + 1];           \
        }                                                                   \
    }

#define LERP_LEVEL(LI)                                                      \
    {   const int l = LVL[w][LI];                                           \
        f16x4 r = lerp4h(c00[LI], c01[LI], c10[LI], c11[LI], fxs[LI], fys[LI]); \
        *(f16x4*)&feT2[(((l >> 1) * PTS + lane) * 8) + (l & 1) * 4] = r; }

    if (QT) {
        // ---- tile 0: issue all, stage W0, lerp ----
        U_SETUP(0)
        ISSUE_LEVEL(0) ISSUE_LEVEL(1) ISSUE_LEVEL(2) ISSUE_LEVEL(3)
        {   // waits only on the 2 oldest (W0) loads
            f16x8* wl = (f16x8*)&w0lds[(size_t)tid * 16];
            wl[0] = wreg0; wl[1] = wreg1;
        }
        LERP_LEVEL(0) LERP_LEVEL(1) LERP_LEVEL(2) LERP_LEVEL(3)
        // ---- pre-issue tile 1 heavies (li=2,3): in flight through MFMA(0) ----
        U_SETUP(1)
        ISSUE_LEVEL(2) ISSUE_LEVEL(3)
        BARRIER();                 // feT2(t0) + w0lds visible; vmcnt stays hot
        mfma_epi(0);
        BARRIER();                 // feT2 reads done
        ISSUE_LEVEL(0) ISSUE_LEVEL(1)
        LERP_LEVEL(2) LERP_LEVEL(3) LERP_LEVEL(0) LERP_LEVEL(1)
        // ---- pre-issue tile 2 heavies ----
        U_SETUP(2)
        ISSUE_LEVEL(2) ISSUE_LEVEL(3)
        BARRIER();
        mfma_epi(1);
        BARRIER();
        ISSUE_LEVEL(0) ISSUE_LEVEL(1)
        LERP_LEVEL(2) LERP_LEVEL(3) LERP_LEVEL(0) LERP_LEVEL(1)
        BARRIER();
        mfma_epi(2);
    } else {
        // fallback: unpipelined 3-tile loop from original f32 table
        {
            f16x8* wl = (f16x8*)&w0lds[(size_t)tid * 16];
            wl[0] = wreg0; wl[1] = wreg1;
        }
        for (int it = 0; it < 3; ++it) {
            U_SETUP(it)
            #pragma unroll
            for (int li = 0; li < 4; ++li) {
                const int l = LVL[w][li];
                const float s = lp.s[l];
                float posx = ux * s + 0.5f, posy = uy * s + 0.5f;
                float pfx = floorf(posx), pfy = floorf(posy);
                float fx = posx - pfx, fy = posy - pfy;
                int cx = (int)pfx, cy = (int)pfy;
                int i00, i01, i10, i11;
                if (lp.mode[l] == 2) {
                    unsigned hy0 = (unsigned)cy * HASH_PRIME;
                    unsigned hy1 = hy0 + HASH_PRIME;
                    i00 = (int)(((unsigned)cx ^ hy0) & TMASK);
                    i01 = (int)(((unsigned)cx ^ hy1) & TMASK);
                    i10 = (int)(((unsigned)(cx + 1) ^ hy0) & TMASK);
                    i11 = (int)(((unsigned)(cx + 1) ^ hy1) & TMASK);
                } else {
                    const int res = lp.res[l];
                    i00 = cy * res + cx; i10 = i00 + 1;
                    i01 = i00 + res;     i11 = i01 + 1;
                }
                const f32x4* tb = (const f32x4*)(emb + (size_t)l * (TABLE_SIZE * 4));
                f32x4 a = tb[i00], b = tb[i01], c = tb[i10], d = tb[i11];
                f16x4 r = lerp4f(a, b, c, d, fx, fy);
                *(f16x4*)&feT2[(((l >> 1) * PTS + lane) * 8) + (l & 1) * 4] = r;
            }
            BARRIER();
            mfma_epi(it);
            BARRIER();
        }
    }
#undef U_SETUP
#undef ISSUE_LEVEL
#undef LERP_LEVEL
}

extern "C" void kernel_launch(void* const* d_in, const int* in_sizes, int n_in,
                              void* d_out, int out_size, void* d_ws, size_t ws_size,
                              hipStream_t stream) {
    const float* x   = (const float*)d_in[0];
    const float* emb = (const float*)d_in[1];
    const float* W0  = (const float*)d_in[2];
    const float* b0  = (const float*)d_in[3];
    const float* W1  = (const float*)d_in[4];
    const float* b1  = (const float*)d_in[5];
    float* out = (float*)d_out;

    // ws layout: [0,8192) w0f; [8192, 8192+128K) rayBuf; embq at 147456.
    char*  ws     = (char*)d_ws;
    f16*   w0f    = (f16*)ws;
    float* rayBuf = (float*)(ws + 8192);
    char*  embq   = ws + 147456;

    // Replicate numpy's level constants with the same host libm double ops.
    LvlParams lp;
    const double bb = std::exp((std::log(2048.0) - std::log(2.0)) / 15.0);
    int offB = 0, maxUsed = 0;
    for (int l = 0; l < NUM_LEVELS; ++l) {
        double sc = 2.0 * std::pow(bb, (double)l) - 1.0;
        int rr = (int)std::ceil(sc) + 1;
        lp.s[l] = (float)sc;
        lp.res[l] = rr;
        const bool hashed = ((long long)rr * (long long)rr > (long long)TABLE_SIZE);
        int used;
        if (hashed) {
            used = TABLE_SIZE;
        } else {
            // Reference does NOT clamp corners: max idx = cmax*res + cmax where
            // cmax = floor(s+0.5)+1 (reachable at u=1). Cover it, + margin for
            // float(s) vs double(s) coordinate rounding.
            long long cmax = (long long)std::floor(sc + 0.5) + 1;
            long long u = cmax * (long long)rr + cmax + 1 + (rr + 2);
            used = (int)std::min((long long)TABLE_SIZE, u);
        }
        // mode: hashed=2; quad only where sample stride >= ~1 cell (res >= 150):
        // coarse levels stay plain 8B so they remain L1/L2-resident.
        lp.mode[l] = hashed ? 2 : (rr >= 150 ? 1 : 0);
        lp.offB[l] = offB;
        lp.used[l] = used;
        const long long bytes = (lp.mode[l] == 1) ? (long long)used * 32
                                                  : (long long)used * 8;
        offB += (int)((bytes + 4095) & ~4095LL);      // keep levels 4KB-aligned
        if (used > maxUsed) maxUsed = used;
    }
    const size_t need = 147456 + (size_t)offB;         // ~26 MB
    const bool useQ = ws_size >= need;

    const int nblk = out_size / T_SAMPLES;   // 8192 rays, one per block
    if (useQ) {
        dim3 pg((maxUsed + CHUNK - 1) / CHUNK, NUM_LEVELS);
        prep_tables<<<pg, 256, 0, stream>>>(emb, embq, W0, w0f, x, rayBuf, lp);
        nerf_fused<true><<<nblk, BLOCK, 0, stream>>>(x, emb, embq, w0f, rayBuf,
                                                     b0, W1, b1, out, lp);
    } else {
        // fallback still needs w0f: pack it with a tiny grid (block (0,0) only)
        dim3 pg1(1, 1);
        prep_tables<<<pg1, 256, 0, stream>>>(emb, embq, W0, w0f, x, rayBuf, lp);
        nerf_fused<false><<<nblk, BLOCK, 0, stream>>>(x, emb, embq, w0f, rayBuf,
                                                      b0, W1, b1, out, lp);
    }
}

// Round 9
// 324.475 us; speedup vs baseline: 1.1551x; 1.1551x over previous
//
#include <hip/hip_runtime.h>
#include <cmath>
#include <algorithm>

#define NUM_LEVELS 16
#define TABLE_SIZE 524288
#define TMASK (TABLE_SIZE - 1)
#define HASH_PRIME 2654435761u
#define T_SAMPLES 192
#define BLOCK 256
#define PTS 64          // points per tile; 4 waves split the 16 levels
#define CHUNK 4096      // entries per conversion chunk
#define N_RAYS 8192

typedef _Float16 f16;
typedef f16 f16x4 __attribute__((ext_vector_type(4)));
typedef f16 f16x8 __attribute__((ext_vector_type(8)));
typedef float f32x4 __attribute__((ext_vector_type(4)));

// mode per level: 0 = plain f16 entries (8B), 1 = quad-replicated 32B slots,
//                 2 = hashed, plain f16 entries (8B)
struct LvlParams {
    float s[NUM_LEVELS];
    int   res[NUM_LEVELS];
    int   mode[NUM_LEVELS];
    int   offB[NUM_LEVELS];   // BYTE offset of level table in embq (4096-aligned)
    int   used[NUM_LEVELS];   // entries actually referenced at this level
};

#define C_10L2E  14.42695040888963f          // 10*log2(e)
#define C_LN2_01 0.0693147180559945f         // ln(2)*0.1

// base-2 HW transcendentals (v_exp_f32 / v_log_f32 are base-2 on AMD)
#define EXP2F(x) __builtin_amdgcn_exp2f(x)
#define LOG2F(x) __builtin_amdgcn_logf(x)

// Wave->level assignment, balanced by gather cost. li=2,3 are the EXPENSIVE
// levels (hashed/quad): tile i+1's li=2,3 gathers are issued BEFORE tile i's
// MFMA (same barrier-free region) so their latency hides under compute.
__device__ __constant__ const int LVL[4][4] = {
    {0, 1, 8, 13},
    {2, 3, 7, 14},
    {4, 5, 6, 15},
    {9, 10, 11, 12},
};

// Packed-f16 bilinear lerp: corners arrive as packed f16 pairs straight from
// the gather (no unpack/dequant).
__device__ __forceinline__ f16x4 lerp4h(f16x4 c00, f16x4 c01, f16x4 c10, f16x4 c11,
                                        float fx, float fy) {
    float gx = 1.0f - fx, gy = 1.0f - fy;
    f16 w00 = (f16)(gx * gy), w01 = (f16)(gx * fy);
    f16 w10 = (f16)(fx * gy), w11 = (f16)(fx * fy);
    f16x4 v00 = {w00, w00, w00, w00}, v01 = {w01, w01, w01, w01};
    f16x4 v10 = {w10, w10, w10, w10}, v11 = {w11, w11, w11, w11};
    return c00 * v00 + c01 * v01 + c10 * v10 + c11 * v11;
}

// fp32 fallback lerp (QT=false path), result rounded to f16 for the MFMA.
__device__ __forceinline__ f16x4 lerp4f(f32x4 c00, f32x4 c01, f32x4 c10, f32x4 c11,
                                        float fx, float fy) {
    float w00 = (1.0f - fx) * (1.0f - fy), w01 = (1.0f - fx) * fy;
    float w10 = fx * (1.0f - fy),          w11 = fx * fy;
    f32x4 a = c00 * w00 + c01 * w01 + c10 * w10 + c11 * w11;
    return __builtin_convertvector(a, f16x4);
}

// ---- prep_tables (merged with W0 pack + per-ray setup) ----
__global__ void prep_tables(const float* __restrict__ emb, char* __restrict__ embq,
                            const float* __restrict__ W0, f16* __restrict__ w0f,
                            const float* __restrict__ x, float* __restrict__ rayBuf,
                            const LvlParams lp) {
    const int t = threadIdx.x;
    if (blockIdx.x == 0 && blockIdx.y == 0) {
        // pack W0 into MFMA-B-fragment f16 order
        #pragma unroll
        for (int i = 0; i < 16; ++i) {
            int f = t * 16 + i;
            int j = f & 7, lx = (f >> 3) & 15, q = (f >> 7) & 3, nt = (f >> 9) & 3, kc = f >> 11;
            w0f[f] = (f16)W0[(kc * 32 + q * 8 + j) * 64 + (nt * 16 + lx)];
        }
    }
    if (blockIdx.y == 1 && blockIdx.x < (N_RAYS / 256)) {
        const int ray = blockIdx.x * 256 + t;
        const float2 o  = *(const float2*)(x + (size_t)ray * (T_SAMPLES * 2));
        const float2 ep = *(const float2*)(x + (size_t)ray * (T_SAMPLES * 2) + (T_SAMPLES - 1) * 2);
        float rdx = ep.x - o.x, rdy = ep.y - o.y;
        float inv = 1.0f / sqrtf(rdx * rdx + rdy * rdy);
        f32x4 rb; rb.x = o.x; rb.y = o.y; rb.z = rdx * inv; rb.w = rdy * inv;
        *(f32x4*)(rayBuf + (size_t)ray * 4) = rb;
    }
    const int l    = blockIdx.y;
    const int used = lp.used[l];
    const int base = blockIdx.x * CHUNK;          // entry base within level
    if (base >= used) return;
    const float* src = emb + (size_t)l * TABLE_SIZE * 4;
    char* dst = embq + lp.offB[l];
    if (lp.mode[l] == 1) {
        const int res = lp.res[l];
        #pragma unroll
        for (int i = 0; i < 16; ++i) {
            int e = base + t + 256 * i;
            if (e < used) {
                f32x4 v00 = *(const f32x4*)(src + (size_t)e * 4);
                f32x4 v10 = *(const f32x4*)(src + (size_t)(e + 1) * 4);
                f32x4 v01 = *(const f32x4*)(src + (size_t)(e + res) * 4);
                f32x4 v11 = *(const f32x4*)(src + (size_t)(e + res + 1) * 4);
                f16x4 a = __builtin_convertvector(v00, f16x4);
                f16x4 b = __builtin_convertvector(v10, f16x4);
                f16x4 c = __builtin_convertvector(v01, f16x4);
                f16x4 d = __builtin_convertvector(v11, f16x4);
                f16x8 q0 = __builtin_shufflevector(a, b, 0, 1, 2, 3, 4, 5, 6, 7);
                f16x8 q1 = __builtin_shufflevector(c, d, 0, 1, 2, 3, 4, 5, 6, 7);
                *(f16x8*)(dst + ((size_t)e << 5))      = q0;
                *(f16x8*)(dst + ((size_t)e << 5) + 16) = q1;
            }
        }
    } else {
        #pragma unroll
        for (int i = 0; i < 16; ++i) {
            int e = base + t + 256 * i;
            if (e < used) {
                f32x4 v = *(const f32x4*)(src + (size_t)e * 4);
                *(f16x4*)(dst + (size_t)e * 8) = __builtin_convertvector(v, f16x4);
            }
        }
    }
}

// One ray (192 points = 3 tiles of 64) per block. Double-buffered feature
// tile -> ONE plain __syncthreads per tile; tile i+1's heavy gathers are
// issued before tile i's MFMA inside the same barrier-free region (plain
// loads into VGPRs; the barrier's vmcnt drain lands after the lerp consumed
// them). No raw barriers, no asm -> no reload storm, no spill cliff
// (launch_bounds(256,6) gives an 85-VGPR cap; LDS caps residency at 6
// blocks/CU = 75% occupancy, which equals what we measure anyway).
template<bool QT>
__launch_bounds__(BLOCK, 6)
__global__ void nerf_fused(const float* __restrict__ x,
                           const float* __restrict__ emb,
                           const char* __restrict__ embq,
                           const f16* __restrict__ w0f,
                           const float* __restrict__ rayBuf,
                           const float* __restrict__ b0,
                           const float* __restrict__ W1,
                           const float* __restrict__ b1,
                           float* __restrict__ out,
                           const LvlParams lp) {
    // feT2[buf][pair][point][8]: MFMA A-fragment = 1 ds_read_b128. 2 x 8 KB.
    __shared__ __align__(16) f16 feT2[2][4096];
    __shared__ __align__(16) f16 w0lds[4096];         // 8 KB

    const int tid  = threadIdx.x;
    const int lane = tid & 63;
    const int w    = __builtin_amdgcn_readfirstlane(tid >> 6);   // wave-uniform

    // ---- W0 staging loads FIRST (oldest in vmcnt FIFO) ----
    f16x8 wreg0, wreg1;
    {
        const f16x8* wp = (const f16x8*)(w0f + (size_t)tid * 16);
        wreg0 = wp[0]; wreg1 = wp[1];
    }

    const int ray = blockIdx.x;                       // ONE ray per block

    f32x4 rb;                                         // {ox, oy, rdx_n, rdy_n}
    if (QT) {
        rb = *(const f32x4*)(rayBuf + (size_t)ray * 4);
    } else {
        const float2 o  = *(const float2*)(x + (size_t)ray * (T_SAMPLES * 2));
        const float2 ep = *(const float2*)(x + (size_t)ray * (T_SAMPLES * 2) + (T_SAMPLES - 1) * 2);
        float rdx = ep.x - o.x, rdy = ep.y - o.y;
        float inv = 1.0f / sqrtf(rdx * rdx + rdy * rdy);
        rb.x = o.x; rb.y = o.y; rb.z = rdx * inv; rb.w = rdy * inv;
    }

    // ---- epilogue constants (loaded once per ray) ----
    const int lx = lane & 15, q = lane >> 4;
    float b0l2[4], w1l2[4];
    #pragma unroll
    for (int nt = 0; nt < 4; ++nt) {
        b0l2[nt] = b0[nt * 16 + lx] * C_10L2E;
        w1l2[nt] = W1[nt * 16 + lx] * C_LN2_01;
    }
    const float b1v = b1[0];
    const int p = w * 16 + lx;

    // ---- MLP + epilogue for the tile staged in feT2[buf] ----
    auto mfma_epi = [&](int tileIdx, int buf) {
        const f16* ft = feT2[buf];
        f32x4 acc[4];
        #pragma unroll
        for (int nt = 0; nt < 4; ++nt) acc[nt] = (f32x4)(0.0f);
        #pragma unroll
        for (int kc = 0; kc < 2; ++kc) {
            f16x8 afr = *(const f16x8*)&ft[((kc * 4 + q) * PTS + p) * 8];
            #pragma unroll
            for (int nt = 0; nt < 4; ++nt) {
                f16x8 bfr = *(const f16x8*)&w0lds[(size_t)(((kc * 4 + nt) * 4 + q) * 16 + lx) * 8];
                acc[nt] = __builtin_amdgcn_mfma_f32_16x16x32_f16(afr, bfr, acc[nt], 0, 0, 0);
            }
        }
        const float d0 = (float)(1.0 / 192.0);
        const float d1 = (float)(2.0 / 191.0);
        float part[4];
        #pragma unroll
        for (int r = 0; r < 4; ++r) {
            float pp = 0.0f;
            #pragma unroll
            for (int nt = 0; nt < 4; ++nt) {
                float t2 = fmaf(acc[nt][r], C_10L2E, b0l2[nt]);
                float e2 = EXP2F(-fabsf(t2));
                float sp = fmaxf(t2, 0.0f) + LOG2F(1.0f + e2);
                pp = fmaf(sp, w1l2[nt], pp);
            }
            pp += __shfl_xor(pp, 1, 64);
            pp += __shfl_xor(pp, 2, 64);
            pp += __shfl_xor(pp, 4, 64);
            pp += __shfl_xor(pp, 8, 64);
            part[r] = pp;
        }
        if (lx == 0) {
            const int tt0 = tileIdx * PTS + w * 16 + q * 4;   // t within ray
            const int g0  = ray * T_SAMPLES + tt0;
            const float dd0 = d0 * C_LN2_01, dd1 = d1 * C_LN2_01;
            f32x4 ov;
            #pragma unroll
            for (int r = 0; r < 4; ++r) {
                float t2 = (part[r] + b1v) * C_10L2E;
                float e2 = EXP2F(-fabsf(t2));
                float sp = fmaxf(t2, 0.0f) + LOG2F(1.0f + e2);
                ov[r] = sp * ((r == 0 && tt0 == 0) ? dd0 : dd1);
            }
            *(f32x4*)(out + g0) = ov;
        }
    };

    float ux, uy;
    f16x4 c00[4], c01[4], c10[4], c11[4];
    float fxs[4], fys[4];

#define U_SETUP(IT)                                                         \
    {   const float z = (float)((double)((IT) * PTS + lane) * (2.0 / 191.0)); \
        float px = fminf(fmaxf(rb.x + rb.z * z, -1.0f), 1.0f);              \
        float py = fminf(fmaxf(rb.y + rb.w * z, -1.0f), 1.0f);              \
        ux = (px + 1.0f) * 0.5f; uy = (py + 1.0f) * 0.5f; }

#define ISSUE_LEVEL(LI)                                                     \
    {   const int l = LVL[w][LI];                                           \
        const int mode = lp.mode[l];                                        \
        const float s = lp.s[l];                                            \
        float posx = ux * s + 0.5f, posy = uy * s + 0.5f;                   \
        float pfx = floorf(posx), pfy = floorf(posy);                       \
        fxs[LI] = posx - pfx; fys[LI] = posy - pfy;                         \
        int cx = (int)pfx, cy = (int)pfy;                                   \
        const char* lb = embq + lp.offB[l];                                 \
        if (mode == 2) {                                                    \
            unsigned hy0 = (unsigned)cy * HASH_PRIME;                       \
            unsigned hy1 = hy0 + HASH_PRIME;                                \
            int iA  = (int)(((unsigned)cx ^ hy0) & TMASK);                  \
            int iB  = (int)(((unsigned)cx ^ hy1) & TMASK);                  \
            int iA1 = (int)(((unsigned)(cx + 1) ^ hy0) & TMASK);            \
            int iB1 = (int)(((unsigned)(cx + 1) ^ hy1) & TMASK);            \
            c00[LI] = *(const f16x4*)(lb + ((size_t)iA  << 3));             \
            c01[LI] = *(const f16x4*)(lb + ((size_t)iB  << 3));             \
            c10[LI] = *(const f16x4*)(lb + ((size_t)iA1 << 3));             \
            c11[LI] = *(const f16x4*)(lb + ((size_t)iB1 << 3));             \
        } else if (mode == 1) {                                             \
            int i00 = cy * lp.res[l] + cx;                                  \
            f16x8 q0 = *(const f16x8*)(lb + ((size_t)i00 << 5));            \
            f16x8 q1 = *(const f16x8*)(lb + ((size_t)i00 << 5) + 16);       \
            c00[LI] = __builtin_shufflevector(q0, q0, 0, 1, 2, 3);          \
            c10[LI] = __builtin_shufflevector(q0, q0, 4, 5, 6, 7);          \
            c01[LI] = __builtin_shufflevector(q1, q1, 0, 1, 2, 3);          \
            c11[LI] = __builtin_shufflevector(q1, q1, 4, 5, 6, 7);          \
        } else {                                                            \
            const int res = lp.res[l];                                      \
            int i00 = cy * res + cx;                                        \
            const f16x4* tb = (const f16x4*)lb;                             \
            c00[LI] = tb[i00];       c10[LI] = tb[i00 + 1];                 \
            c01[LI] = tb[i00 + res]; c11[LI] = tb[i00 + res + 1];           \
        }                                                                   \
    }

#define LERP_LEVEL(LI, BUF)                                                 \
    {   const int l = LVL[w][LI];                                           \
        f16x4 r = lerp4h(c00[LI], c01[LI], c10[LI], c11[LI], fxs[LI], fys[LI]); \
        *(f16x4*)&feT2[BUF][(((l >> 1) * PTS + lane) * 8) + (l & 1) * 4] = r; }

    if (QT) {
        // ---- tile 0: issue all, stage W0, lerp -> buf0 ----
        U_SETUP(0)
        ISSUE_LEVEL(0) ISSUE_LEVEL(1) ISSUE_LEVEL(2) ISSUE_LEVEL(3)
        {   // waits only on the 2 oldest (W0) loads
            f16x8* wl = (f16x8*)&w0lds[(size_t)tid * 16];
            wl[0] = wreg0; wl[1] = wreg1;
        }
        LERP_LEVEL(0, 0) LERP_LEVEL(1, 0) LERP_LEVEL(2, 0) LERP_LEVEL(3, 0)
        __syncthreads();
        // ---- region 1: heavies(t1) in flight across mfma(t0) ----
        U_SETUP(1)
        ISSUE_LEVEL(2) ISSUE_LEVEL(3)
        mfma_epi(0, 0);
        ISSUE_LEVEL(0) ISSUE_LEVEL(1)
        LERP_LEVEL(2, 1) LERP_LEVEL(3, 1) LERP_LEVEL(0, 1) LERP_LEVEL(1, 1)
        __syncthreads();
        // ---- region 2: heavies(t2) in flight across mfma(t1) ----
        U_SETUP(2)
        ISSUE_LEVEL(2) ISSUE_LEVEL(3)
        mfma_epi(1, 1);
        ISSUE_LEVEL(0) ISSUE_LEVEL(1)
        LERP_LEVEL(2, 0) LERP_LEVEL(3, 0) LERP_LEVEL(0, 0) LERP_LEVEL(1, 0)
        __syncthreads();
        mfma_epi(2, 0);
    } else {
        // fallback: unpipelined 3-tile loop from original f32 table
        {
            f16x8* wl = (f16x8*)&w0lds[(size_t)tid * 16];
            wl[0] = wreg0; wl[1] = wreg1;
        }
        for (int it = 0; it < 3; ++it) {
            U_SETUP(it)
            #pragma unroll
            for (int li = 0; li < 4; ++li) {
                const int l = LVL[w][li];
                const float s = lp.s[l];
                float posx = ux * s + 0.5f, posy = uy * s + 0.5f;
                float pfx = floorf(posx), pfy = floorf(posy);
                float fx = posx - pfx, fy = posy - pfy;
                int cx = (int)pfx, cy = (int)pfy;
                int i00, i01, i10, i11;
                if (lp.mode[l] == 2) {
                    unsigned hy0 = (unsigned)cy * HASH_PRIME;
                    unsigned hy1 = hy0 + HASH_PRIME;
                    i00 = (int)(((unsigned)cx ^ hy0) & TMASK);
                    i01 = (int)(((unsigned)cx ^ hy1) & TMASK);
                    i10 = (int)(((unsigned)(cx + 1) ^ hy0) & TMASK);
                    i11 = (int)(((unsigned)(cx + 1) ^ hy1) & TMASK);
                } else {
                    const int res = lp.res[l];
                    i00 = cy * res + cx; i10 = i00 + 1;
                    i01 = i00 + res;     i11 = i01 + 1;
                }
                const f32x4* tb = (const f32x4*)(emb + (size_t)l * (TABLE_SIZE * 4));
                f32x4 a = tb[i00], b = tb[i01], c = tb[i10], d = tb[i11];
                f16x4 r = lerp4f(a, b, c, d, fx, fy);
                *(f16x4*)&feT2[it & 1][(((l >> 1) * PTS + lane) * 8) + (l & 1) * 4] = r;
            }
            __syncthreads();
            mfma_epi(it, it & 1);
        }
    }
#undef U_SETUP
#undef ISSUE_LEVEL
#undef LERP_LEVEL
}

extern "C" void kernel_launch(void* const* d_in, const int* in_sizes, int n_in,
                              void* d_out, int out_size, void* d_ws, size_t ws_size,
                              hipStream_t stream) {
    const float* x   = (const float*)d_in[0];
    const float* emb = (const float*)d_in[1];
    const float* W0  = (const float*)d_in[2];
    const float* b0  = (const float*)d_in[3];
    const float* W1  = (const float*)d_in[4];
    const float* b1  = (const float*)d_in[5];
    float* out = (float*)d_out;

    // ws layout: [0,8192) w0f; [8192, 8192+128K) rayBuf; embq at 147456.
    char*  ws     = (char*)d_ws;
    f16*   w0f    = (f16*)ws;
    float* rayBuf = (float*)(ws + 8192);
    char*  embq   = ws + 147456;

    // Replicate numpy's level constants with the same host libm double ops.
    LvlParams lp;
    const double bb = std::exp((std::log(2048.0) - std::log(2.0)) / 15.0);
    int offB = 0, maxUsed = 0;
    for (int l = 0; l < NUM_LEVELS; ++l) {
        double sc = 2.0 * std::pow(bb, (double)l) - 1.0;
        int rr = (int)std::ceil(sc) + 1;
        lp.s[l] = (float)sc;
        lp.res[l] = rr;
        const bool hashed = ((long long)rr * (long long)rr > (long long)TABLE_SIZE);
        int used;
        if (hashed) {
            used = TABLE_SIZE;
        } else {
            // Reference does NOT clamp corners: max idx = cmax*res + cmax where
            // cmax = floor(s+0.5)+1 (reachable at u=1). Cover it, + margin for
            // float(s) vs double(s) coordinate rounding.
            long long cmax = (long long)std::floor(sc + 0.5) + 1;
            long long u = cmax * (long long)rr + cmax + 1 + (rr + 2);
            used = (int)std::min((long long)TABLE_SIZE, u);
        }
        // mode: hashed=2; quad only where sample stride >= ~1 cell (res >= 150):
        // coarse levels stay plain 8B so they remain L1/L2-resident.
        lp.mode[l] = hashed ? 2 : (rr >= 150 ? 1 : 0);
        lp.offB[l] = offB;
        lp.used[l] = used;
        const long long bytes = (lp.mode[l] == 1) ? (long long)used * 32
                                                  : (long long)used * 8;
        offB += (int)((bytes + 4095) & ~4095LL);      // keep levels 4KB-aligned
        if (used > maxUsed) maxUsed = used;
    }
    const size_t need = 147456 + (size_t)offB;         // ~26 MB
    const bool useQ = ws_size >= need;

    const int nblk = out_size / T_SAMPLES;   // 8192 rays, one per block
    if (useQ) {
        dim3 pg((maxUsed + CHUNK - 1) / CHUNK, NUM_LEVELS);
        prep_tables<<<pg, 256, 0, stream>>>(emb, embq, W0, w0f, x, rayBuf, lp);
        nerf_fused<true><<<nblk, BLOCK, 0, stream>>>(x, emb, embq, w0f, rayBuf,
                                                     b0, W1, b1, out, lp);
    } else {
        // fallback still needs w0f: pack it with a tiny grid (block (0,0) only)
        dim3 pg1(1, 1);
        prep_tables<<<pg1, 256, 0, stream>>>(emb, embq, W0, w0f, x, rayBuf, lp);
        nerf_fused<false><<<nblk, BLOCK, 0, stream>>>(x, emb, embq, w0f, rayBuf,
                                                      b0, W1, b1, out, lp);
    }
}